// Round 2
// baseline (1038.213 us; speedup 1.0000x reference)
//
#include <hip/hip_runtime.h>
#include <hip/hip_bf16.h>

#define BATCH 2048
#define KD 1024
#define ND 1024
#define NLEAF 64
#define LPG 8      // leaves per p-group
#define MT 32      // batch rows per block
#define BK 32      // K-step

typedef __attribute__((ext_vector_type(8))) short bf16x8;
typedef __attribute__((ext_vector_type(4))) float f32x4;

// workspace layout (bytes)
#define WLB_OFF 0ULL                 // 64*1024*1024 bf16 = 128 MB
#define XB_OFF  134217728ULL         // 2048*1024 bf16 = 4 MB
#define RT_OFF  138412032ULL         // 2048*64 f32 = 512 KB
#define PT_OFF  138936320ULL         // 8 * 2048*1024 f32 = 64 MB partials

// LDS layout (bytes)
#define SM_B0   0
#define SM_B1   65536
#define SM_A0   131072
#define SM_A1   133120
#define SM_RED  135168
#define SM_TOTAL 136192

__device__ __forceinline__ unsigned short f2bf(float f) {
  unsigned int u = __float_as_uint(f);
  u += 0x7fffu + ((u >> 16) & 1u);   // round-to-nearest-even
  return (unsigned short)(u >> 16);
}

__device__ __forceinline__ void gload_lds16(const void* g, void* l) {
  __builtin_amdgcn_global_load_lds(
      (const __attribute__((address_space(1))) unsigned int*)g,
      (__attribute__((address_space(3))) unsigned int*)l, 16, 0, 0);
}

// ---------------- kernel 1: f32 -> bf16 conversion of Wl and x ----------------
__global__ void __launch_bounds__(256) convert_kernel(
    const float* __restrict__ Wl, const float* __restrict__ x,
    unsigned short* __restrict__ wlb, unsigned short* __restrict__ xb) {
  const long long WL4 = 16777216LL;   // 64M elems / 4
  const long long X4  = 524288LL;     // 2M elems / 4
  long long i = (long long)blockIdx.x * 256 + threadIdx.x;
  const long long stride = (long long)gridDim.x * 256;
  for (; i < WL4 + X4; i += stride) {
    float4 v;
    if (i < WL4) v = ((const float4*)Wl)[i];
    else         v = ((const float4*)x)[i - WL4];
    ushort4 o;
    o.x = f2bf(v.x); o.y = f2bf(v.y); o.z = f2bf(v.z); o.w = f2bf(v.w);
    if (i < WL4) ((ushort4*)wlb)[i] = o;
    else         ((ushort4*)xb)[i - WL4] = o;
  }
}

// ---------------- kernel 2: routing probabilities (f32 exact) ----------------
__global__ void __launch_bounds__(256) routing_kernel(
    const float* __restrict__ x, const float* __restrict__ Wd,
    const float* __restrict__ bd, float* __restrict__ rt) {
  __shared__ float xs[4][KD];
  __shared__ float sdp[4][64];
  const int tid = threadIdx.x;
  const int b0 = blockIdx.x * 4;
  const float4* xsrc = (const float4*)(x + (size_t)b0 * KD);
  float4* xdst = (float4*)&xs[0][0];
  for (int i = tid; i < KD; i += 256) xdst[i] = xsrc[i];
  __syncthreads();
  const int wv = tid >> 6, ln = tid & 63;
  const int b = b0 + wv;
  if (ln < 63) {
    const float4* wrow = (const float4*)(Wd + (size_t)ln * KD);
    const float4* xr = (const float4*)&xs[wv][0];
    float4 a = {0.f, 0.f, 0.f, 0.f};
    for (int k = 0; k < KD / 4; ++k) {
      float4 w = wrow[k], xv = xr[k];
      a.x += w.x * xv.x; a.y += w.y * xv.y; a.z += w.z * xv.z; a.w += w.w * xv.w;
    }
    float z = a.x + a.y + a.z + a.w + bd[ln];
    sdp[wv][ln] = 1.f / (1.f + __expf(-z));
  }
  __syncthreads();
  float prod = 1.f;
  int node = 0, index = ln;
  for (int d = 0; d < 6; ++d) {
    float pv = sdp[wv][node];
    prod *= (index & 1) ? (1.f - pv) : pv;
    node = node * 2 + 1 + (index & 1);
    index >>= 1;
  }
  rt[(size_t)b * NLEAF + ln] = prod;
}

// ------- kernel 3: fused leaf-GEMM (bf16 MFMA) + softmax + weighted sum -------
// Each block: batch tile b0..b0+31 x leaf group p*8..p*8+7; writes an 8-leaf
// PARTIAL routing-weighted sum to its private region of pt. reduce_kernel sums
// the 8 partials -> out.
__global__ void __launch_bounds__(512, 2) fused_kernel(
    const unsigned short* __restrict__ wlb, const unsigned short* __restrict__ xb,
    const float* __restrict__ rt, const float* __restrict__ bl,
    float* __restrict__ pt) {
  extern __shared__ char smem[];
  const int tid = threadIdx.x;
  const int wv  = tid >> 6;       // wave 0..7 -> N cols [wv*128, wv*128+128)
  const int ln  = tid & 63;
  const int g   = ln >> 4;        // k-group of MFMA operand
  const int r16 = ln & 15;        // row within operand 16-tile / col of C/D
  const int p   = blockIdx.x & 7; // leaf group
  const int b0  = (blockIdx.x >> 3) * MT;
  const int rB  = ln >> 2;        // staging: row-in-16 for this lane
  const int cB  = ln & 3;         // staging: 16B chunk within 64B row

  f32x4 oac[2][8];
#pragma unroll
  for (int mi = 0; mi < 2; ++mi)
#pragma unroll
    for (int ni = 0; ni < 8; ++ni) oac[mi][ni] = (f32x4){0.f, 0.f, 0.f, 0.f};

  // chunk-XOR swizzle c ^= (row>>1)&3 applied on the GLOBAL source
  // (global_load_lds writes linearly) and again on ds_read (both-sides rule).
  auto STAGE = [&](int bufi, int lf, int k0) {
    char* bB = smem + (bufi ? SM_B1 : SM_B0);
    char* bA = smem + (bufi ? SM_A1 : SM_A0);
#pragma unroll
    for (int it = 0; it < 8; ++it) {
      const int rowbase = (wv * 8 + it) * 16;
      const int row = rowbase + rB;
      const int csrc = cB ^ ((row >> 1) & 3);
      gload_lds16(wlb + ((size_t)lf << 20) + (size_t)row * KD + k0 + csrc * 8,
                  bB + rowbase * 64);
    }
    if (wv < 2) {
      const int rowbase = wv * 16;
      const int row = rowbase + rB;
      const int csrc = cB ^ ((row >> 1) & 3);
      gload_lds16(xb + (size_t)(b0 + row) * KD + k0 + csrc * 8,
                  bA + rowbase * 64);
    }
  };

  f32x4 lac[2][8];
  float* red = (float*)(smem + SM_RED);

  STAGE(0, p * LPG, 0);
  __syncthreads();          // buf0 ready
  int cur = 0;

  for (int j = 0; j < LPG; ++j) {
    const int l = p * LPG + j;
#pragma unroll
    for (int mi = 0; mi < 2; ++mi)
#pragma unroll
      for (int ni = 0; ni < 8; ++ni) lac[mi][ni] = (f32x4){0.f, 0.f, 0.f, 0.f};

    for (int t = 0; t < 32; ++t) {
      const int s = j * 32 + t;
      if (s + 1 < LPG * 32) {           // prefetch next tile into other buffer
        const int ns = s + 1;
        STAGE(cur ^ 1, p * LPG + (ns >> 5), (ns & 31) * BK);
      }
      const char* bB = smem + (cur ? SM_B1 : SM_B0);
      const char* bA = smem + (cur ? SM_A1 : SM_A0);
      bf16x8 af[2], bfr[8];
#pragma unroll
      for (int mi = 0; mi < 2; ++mi) {
        const int row = mi * 16 + r16;
        const int cc = g ^ ((row >> 1) & 3);
        af[mi] = *(const bf16x8*)(bA + row * 64 + cc * 16);
      }
#pragma unroll
      for (int ni = 0; ni < 8; ++ni) {
        const int row = wv * 128 + ni * 16 + r16;
        const int cc = g ^ ((row >> 1) & 3);
        bfr[ni] = *(const bf16x8*)(bB + row * 64 + cc * 16);
      }
#pragma unroll
      for (int mi = 0; mi < 2; ++mi)
#pragma unroll
        for (int ni = 0; ni < 8; ++ni)
          lac[mi][ni] = __builtin_amdgcn_mfma_f32_16x16x32_bf16(
              af[mi], bfr[ni], lac[mi][ni], 0, 0, 0);
      __syncthreads();    // drains prefetch + protects buffers
      cur ^= 1;
    }

    // ---- softmax over the full N=1024 row + routing-weighted accumulate ----
#pragma unroll
    for (int ni = 0; ni < 8; ++ni) {    // + bl
      const float blv = bl[(size_t)l * ND + wv * 128 + ni * 16 + r16];
#pragma unroll
      for (int mi = 0; mi < 2; ++mi) lac[mi][ni] += blv;
    }
    float rmx[2][4];
#pragma unroll
    for (int mi = 0; mi < 2; ++mi)
#pragma unroll
      for (int q = 0; q < 4; ++q) {
        float m = lac[mi][0][q];
#pragma unroll
        for (int ni = 1; ni < 8; ++ni) m = fmaxf(m, lac[mi][ni][q]);
        rmx[mi][q] = m;
      }
#pragma unroll
    for (int off = 1; off < 16; off <<= 1)
#pragma unroll
      for (int mi = 0; mi < 2; ++mi)
#pragma unroll
        for (int q = 0; q < 4; ++q)
          rmx[mi][q] = fmaxf(rmx[mi][q], __shfl_xor(rmx[mi][q], off));
    if (r16 == 0)
#pragma unroll
      for (int mi = 0; mi < 2; ++mi)
#pragma unroll
        for (int q = 0; q < 4; ++q)
          red[(mi * 16 + g * 4 + q) * 8 + wv] = rmx[mi][q];
    __syncthreads();
#pragma unroll
    for (int mi = 0; mi < 2; ++mi)
#pragma unroll
      for (int q = 0; q < 4; ++q) {
        const int row = mi * 16 + g * 4 + q;
        float m = red[row * 8];
#pragma unroll
        for (int w = 1; w < 8; ++w) m = fmaxf(m, red[row * 8 + w]);
        rmx[mi][q] = m;
      }
    __syncthreads();     // all reads of red done before sum pass rewrites it
    float rsm[2][4];
#pragma unroll
    for (int mi = 0; mi < 2; ++mi)
#pragma unroll
      for (int q = 0; q < 4; ++q) rsm[mi][q] = 0.f;
#pragma unroll
    for (int mi = 0; mi < 2; ++mi)
#pragma unroll
      for (int ni = 0; ni < 8; ++ni)
#pragma unroll
        for (int q = 0; q < 4; ++q) {
          const float e = __expf(lac[mi][ni][q] - rmx[mi][q]);
          lac[mi][ni][q] = e;
          rsm[mi][q] += e;
        }
#pragma unroll
    for (int off = 1; off < 16; off <<= 1)
#pragma unroll
      for (int mi = 0; mi < 2; ++mi)
#pragma unroll
        for (int q = 0; q < 4; ++q)
          rsm[mi][q] += __shfl_xor(rsm[mi][q], off);
    if (r16 == 0)
#pragma unroll
      for (int mi = 0; mi < 2; ++mi)
#pragma unroll
        for (int q = 0; q < 4; ++q)
          red[(mi * 16 + g * 4 + q) * 8 + wv] = rsm[mi][q];
    __syncthreads();
#pragma unroll
    for (int mi = 0; mi < 2; ++mi)
#pragma unroll
      for (int q = 0; q < 4; ++q) {
        const int row = mi * 16 + g * 4 + q;
        float S = red[row * 8];
#pragma unroll
        for (int w = 1; w < 8; ++w) S += red[row * 8 + w];
        const float coef = rt[(size_t)(b0 + row) * NLEAF + l] / S;
#pragma unroll
        for (int ni = 0; ni < 8; ++ni)
          oac[mi][ni][q] += coef * lac[mi][ni][q];
      }
    // no extra barrier: next write to `red` is >=32 barriers away
  }

  // epilogue: write this block's 8-leaf partial to its private region
  float* myp = pt + (size_t)p * BATCH * ND;
#pragma unroll
  for (int mi = 0; mi < 2; ++mi)
#pragma unroll
    for (int q = 0; q < 4; ++q) {
      const int row = b0 + mi * 16 + g * 4 + q;
#pragma unroll
      for (int ni = 0; ni < 8; ++ni) {
        const int col = wv * 128 + ni * 16 + r16;
        myp[(size_t)row * ND + col] = oac[mi][ni][q];
      }
    }
}

// ---------------- kernel 4: sum the 8 leaf-group partials ----------------
__global__ void __launch_bounds__(256) reduce_kernel(
    const float* __restrict__ pt, float* __restrict__ out) {
  const size_t stride4 = (size_t)BATCH * ND / 4;   // 524288 float4s
  size_t i = (size_t)blockIdx.x * 256 + threadIdx.x;
  float4 a = ((const float4*)pt)[i];
#pragma unroll
  for (int p = 1; p < 8; ++p) {
    float4 b = ((const float4*)pt)[p * stride4 + i];
    a.x += b.x; a.y += b.y; a.z += b.z; a.w += b.w;
  }
  ((float4*)out)[i] = a;
}

extern "C" void kernel_launch(void* const* d_in, const int* in_sizes, int n_in,
                              void* d_out, int out_size, void* d_ws, size_t ws_size,
                              hipStream_t stream) {
  const float* x  = (const float*)d_in[0];
  const float* Wd = (const float*)d_in[1];
  const float* bd = (const float*)d_in[2];
  const float* Wl = (const float*)d_in[3];
  const float* bl = (const float*)d_in[4];
  float* out = (float*)d_out;
  char* ws = (char*)d_ws;
  unsigned short* wlb = (unsigned short*)(ws + WLB_OFF);
  unsigned short* xb  = (unsigned short*)(ws + XB_OFF);
  float* rt           = (float*)(ws + RT_OFF);
  float* pt           = (float*)(ws + PT_OFF);

  convert_kernel<<<2048, 256, 0, stream>>>(Wl, x, wlb, xb);
  routing_kernel<<<BATCH / 4, 256, 0, stream>>>(x, Wd, bd, rt);
  hipFuncSetAttribute((const void*)fused_kernel,
                      hipFuncAttributeMaxDynamicSharedMemorySize, SM_TOTAL);
  fused_kernel<<<(BATCH / MT) * 8, 512, SM_TOTAL, stream>>>(wlb, xb, rt, bl, pt);
  reduce_kernel<<<(BATCH * ND / 4) / 256, 256, 0, stream>>>(pt, out);
}

// Round 3
// 604.247 us; speedup vs baseline: 1.7182x; 1.7182x over previous
//
#include <hip/hip_runtime.h>
#include <hip/hip_bf16.h>

#define BATCH 2048
#define KD 1024
#define ND 1024
#define NLEAF 64
#define NGRP 4            // leaf groups
#define LPG 16            // leaves per group
#define NG (LPG * ND)     // GEMM N per group = 16384

typedef __attribute__((ext_vector_type(8))) short bf16x8;
typedef __attribute__((ext_vector_type(4))) float f32x4;
typedef __attribute__((ext_vector_type(4))) _Float16 f16x4;

// workspace layout (bytes) — total ~203 MB (round-2 proven size)
#define WLB_OFF 0ULL                 // 64*1024*1024 bf16 = 128 MB
#define XB_OFF  134217728ULL         // 2048*1024 bf16 = 4 MB
#define RT_OFF  138412032ULL         // 2048*64 f32 = 512 KB
#define LG_OFF  138936320ULL         // 2048*16384 fp16 = 64 MB logits chunk

__device__ __forceinline__ unsigned short f2bf(float f) {
  unsigned int u = __float_as_uint(f);
  u += 0x7fffu + ((u >> 16) & 1u);   // round-to-nearest-even
  return (unsigned short)(u >> 16);
}

__device__ __forceinline__ void gload_lds16(const void* g, void* l) {
  __builtin_amdgcn_global_load_lds(
      (const __attribute__((address_space(1))) unsigned int*)g,
      (__attribute__((address_space(3))) unsigned int*)l, 16, 0, 0);
}

// ---------------- kernel 1: f32 -> bf16 conversion of Wl and x ----------------
__global__ void __launch_bounds__(256) convert_kernel(
    const float* __restrict__ Wl, const float* __restrict__ x,
    unsigned short* __restrict__ wlb, unsigned short* __restrict__ xb) {
  const long long WL4 = 16777216LL;   // 64M elems / 4
  const long long X4  = 524288LL;     // 2M elems / 4
  long long i = (long long)blockIdx.x * 256 + threadIdx.x;
  const long long stride = (long long)gridDim.x * 256;
  for (; i < WL4 + X4; i += stride) {
    float4 v;
    if (i < WL4) v = ((const float4*)Wl)[i];
    else         v = ((const float4*)x)[i - WL4];
    ushort4 o;
    o.x = f2bf(v.x); o.y = f2bf(v.y); o.z = f2bf(v.z); o.w = f2bf(v.w);
    if (i < WL4) ((ushort4*)wlb)[i] = o;
    else         ((ushort4*)xb)[i - WL4] = o;
  }
}

// ---------------- kernel 2: routing probabilities (f32 exact) ----------------
__global__ void __launch_bounds__(256) routing_kernel(
    const float* __restrict__ x, const float* __restrict__ Wd,
    const float* __restrict__ bd, float* __restrict__ rt) {
  __shared__ float xs[4][KD];
  __shared__ float sdp[4][64];
  const int tid = threadIdx.x;
  const int b0 = blockIdx.x * 4;
  const float4* xsrc = (const float4*)(x + (size_t)b0 * KD);
  float4* xdst = (float4*)&xs[0][0];
  for (int i = tid; i < KD; i += 256) xdst[i] = xsrc[i];
  __syncthreads();
  const int wv = tid >> 6, ln = tid & 63;
  const int b = b0 + wv;
  if (ln < 63) {
    const float4* wrow = (const float4*)(Wd + (size_t)ln * KD);
    const float4* xr = (const float4*)&xs[wv][0];
    float4 a = {0.f, 0.f, 0.f, 0.f};
    for (int k = 0; k < KD / 4; ++k) {
      float4 w = wrow[k], xv = xr[k];
      a.x += w.x * xv.x; a.y += w.y * xv.y; a.z += w.z * xv.z; a.w += w.w * xv.w;
    }
    float z = a.x + a.y + a.z + a.w + bd[ln];
    sdp[wv][ln] = 1.f / (1.f + __expf(-z));
  }
  __syncthreads();
  float prod = 1.f;
  int node = 0, index = ln;
  for (int d = 0; d < 6; ++d) {
    float pv = sdp[wv][node];
    prod *= (index & 1) ? (1.f - pv) : pv;
    node = node * 2 + 1 + (index & 1);
    index >>= 1;
  }
  rt[(size_t)b * NLEAF + ln] = prod;
}

// ---------------- kernel 3: 128x128 bf16 GEMM -> fp16 logits chunk -----------
// A = xb [2048][1024] bf16 (M x K), B = wlb group base [16384][1024] bf16
// (N x K, i.e. B^T), C = logits [2048][16384] fp16.
// m97-style: 4 waves (2x2), acc 4x4 frags/wave, BK=32, double-buffered
// global_load_lds staging with chunk-XOR swizzle on both sides.
__global__ void __launch_bounds__(256, 4) gemm_kernel(
    const unsigned short* __restrict__ A, const unsigned short* __restrict__ B,
    _Float16* __restrict__ C) {
  __shared__ char smem[32768];   // As[2][128][64B] @0, Bs[2][128][64B] @16384
  const int tid = threadIdx.x;
  const int w = tid >> 6, ln = tid & 63;
  const int wr = w >> 1, wc = w & 1;
  const int g = ln >> 4, r16 = ln & 15;
  const int bm = ((int)blockIdx.x & 15) * 128;   // consecutive blocks share B
  const int bn = ((int)blockIdx.x >> 4) * 128;
  const int rS = w * 16 + (ln >> 2);   // staging row within 64-row pass
  const int cS = ln & 3;               // staging 16B chunk

  auto STAGE = [&](int buf, int k0) {
    char* As = smem + buf * 8192;
    char* Bs = smem + 16384 + buf * 8192;
#pragma unroll
    for (int pass = 0; pass < 2; ++pass) {
      const int row = pass * 64 + rS;
      const int csrc = cS ^ ((row >> 1) & 3);
      gload_lds16(A + (size_t)(bm + row) * KD + k0 + csrc * 8,
                  As + pass * 4096 + w * 1024);
      gload_lds16(B + (size_t)(bn + row) * KD + k0 + csrc * 8,
                  Bs + pass * 4096 + w * 1024);
    }
  };

  f32x4 acc[4][4];
#pragma unroll
  for (int mi = 0; mi < 4; ++mi)
#pragma unroll
    for (int ni = 0; ni < 4; ++ni) acc[mi][ni] = (f32x4){0.f, 0.f, 0.f, 0.f};

  STAGE(0, 0);
  __syncthreads();
  int cur = 0;
  for (int t = 0; t < 32; ++t) {
    if (t + 1 < 32) STAGE(cur ^ 1, (t + 1) * 32);
    const char* As = smem + cur * 8192;
    const char* Bs = smem + 16384 + cur * 8192;
    bf16x8 af[4], bfr[4];
#pragma unroll
    for (int mi = 0; mi < 4; ++mi) {
      const int row = wr * 64 + mi * 16 + r16;
      const int cc = g ^ ((row >> 1) & 3);
      af[mi] = *(const bf16x8*)(As + row * 64 + cc * 16);
    }
#pragma unroll
    for (int ni = 0; ni < 4; ++ni) {
      const int row = wc * 64 + ni * 16 + r16;
      const int cc = g ^ ((row >> 1) & 3);
      bfr[ni] = *(const bf16x8*)(Bs + row * 64 + cc * 16);
    }
#pragma unroll
    for (int mi = 0; mi < 4; ++mi)
#pragma unroll
      for (int ni = 0; ni < 4; ++ni)
        acc[mi][ni] = __builtin_amdgcn_mfma_f32_16x16x32_bf16(
            af[mi], bfr[ni], acc[mi][ni], 0, 0, 0);
    __syncthreads();   // drains prefetch (vmcnt 0) + protects buffers
    cur ^= 1;
  }

  // epilogue: C/D layout col=r16, row=g*4+q (verified m89 mapping)
#pragma unroll
  for (int mi = 0; mi < 4; ++mi)
#pragma unroll
    for (int q = 0; q < 4; ++q) {
      const int grow = bm + wr * 64 + mi * 16 + g * 4 + q;
#pragma unroll
      for (int ni = 0; ni < 4; ++ni) {
        const int gcol = bn + wc * 64 + ni * 16 + r16;
        C[(size_t)grow * NG + gcol] = (_Float16)acc[mi][ni][q];
      }
    }
}

// ------- kernel 4: softmax over each leaf row + routing-weighted reduce -------
// One block per batch row b; loops the group's 16 leaves; accumulates into out.
__global__ void __launch_bounds__(256) smax_kernel(
    const _Float16* __restrict__ Cg, const float* __restrict__ rt,
    const float* __restrict__ bl, float* __restrict__ out,
    int grp, int first) {
  __shared__ float redm[4], reds[4];
  const int tid = threadIdx.x;
  const int b = blockIdx.x;
  const int w = tid >> 6, ln = tid & 63;
  const int c0 = tid * 4;
  float oacc[4] = {0.f, 0.f, 0.f, 0.f};

  for (int j = 0; j < LPG; ++j) {
    const int l = grp * LPG + j;
    const f16x4 h = *(const f16x4*)(Cg + (size_t)b * NG + j * ND + c0);
    const float4 blv = *(const float4*)(bl + (size_t)l * ND + c0);
    float v[4];
    v[0] = (float)h[0] + blv.x; v[1] = (float)h[1] + blv.y;
    v[2] = (float)h[2] + blv.z; v[3] = (float)h[3] + blv.w;
    // row max over 1024
    float m = fmaxf(fmaxf(v[0], v[1]), fmaxf(v[2], v[3]));
#pragma unroll
    for (int off = 1; off < 64; off <<= 1) m = fmaxf(m, __shfl_xor(m, off));
    if (ln == 0) redm[w] = m;
    __syncthreads();
    m = fmaxf(fmaxf(redm[0], redm[1]), fmaxf(redm[2], redm[3]));
    // exp + row sum
    float e[4], s = 0.f;
#pragma unroll
    for (int k = 0; k < 4; ++k) { e[k] = __expf(v[k] - m); s += e[k]; }
#pragma unroll
    for (int off = 1; off < 64; off <<= 1) s += __shfl_xor(s, off);
    if (ln == 0) reds[w] = s;
    __syncthreads();
    const float S = reds[0] + reds[1] + reds[2] + reds[3];
    const float coef = rt[(size_t)b * NLEAF + l] / S;
#pragma unroll
    for (int k = 0; k < 4; ++k) oacc[k] += coef * e[k];
  }

  float* orow = out + (size_t)b * ND + c0;
  if (first) {
    *(float4*)orow = (float4){oacc[0], oacc[1], oacc[2], oacc[3]};
  } else {
    float4 p = *(const float4*)orow;
    p.x += oacc[0]; p.y += oacc[1]; p.z += oacc[2]; p.w += oacc[3];
    *(float4*)orow = p;
  }
}

extern "C" void kernel_launch(void* const* d_in, const int* in_sizes, int n_in,
                              void* d_out, int out_size, void* d_ws, size_t ws_size,
                              hipStream_t stream) {
  const float* x  = (const float*)d_in[0];
  const float* Wd = (const float*)d_in[1];
  const float* bd = (const float*)d_in[2];
  const float* Wl = (const float*)d_in[3];
  const float* bl = (const float*)d_in[4];
  float* out = (float*)d_out;
  char* ws = (char*)d_ws;
  unsigned short* wlb = (unsigned short*)(ws + WLB_OFF);
  unsigned short* xb  = (unsigned short*)(ws + XB_OFF);
  float* rt           = (float*)(ws + RT_OFF);
  _Float16* lg        = (_Float16*)(ws + LG_OFF);

  convert_kernel<<<2048, 256, 0, stream>>>(Wl, x, wlb, xb);
  routing_kernel<<<BATCH / 4, 256, 0, stream>>>(x, Wd, bd, rt);
  for (int grp = 0; grp < NGRP; ++grp) {
    gemm_kernel<<<16 * (NG / 128), 256, 0, stream>>>(
        xb, wlb + (size_t)grp * NG * KD, lg);
    smax_kernel<<<BATCH, 256, 0, stream>>>(lg, rt, bl, out, grp, grp == 0);
  }
}

// Round 4
// 521.218 us; speedup vs baseline: 1.9919x; 1.1593x over previous
//
#include <hip/hip_runtime.h>
#include <hip/hip_bf16.h>

#define BATCH 2048
#define KD 1024
#define ND 1024
#define NLEAF 64
#define BM 256
#define BN 256
#define BKT 32              // K elements per pipeline step
#define NKT (KD / BKT)      // 32 steps

typedef __attribute__((ext_vector_type(8))) short bf16x8;
typedef __attribute__((ext_vector_type(4))) float f32x4;
typedef __attribute__((ext_vector_type(4))) _Float16 f16x4;

// workspace layout (bytes)
#define WLB_OFF 0ULL                 // 64M bf16 = 128 MB
#define XB_OFF  134217728ULL         // 2M bf16 = 4 MB
#define RT_OFF  138412032ULL         // 512 KB
#define LG_OFF  138936320ULL         // logits fp16 (268 MB full / 64 MB grouped)

__device__ __forceinline__ unsigned short f2bf(float f) {
  unsigned int u = __float_as_uint(f);
  u += 0x7fffu + ((u >> 16) & 1u);
  return (unsigned short)(u >> 16);
}

__device__ __forceinline__ void gload_lds16(const void* g, void* l) {
  __builtin_amdgcn_global_load_lds(
      (const __attribute__((address_space(1))) unsigned int*)g,
      (__attribute__((address_space(3))) unsigned int*)l, 16, 0, 0);
}

// ---------------- kernel 1: f32 -> bf16 conversion of Wl and x ----------------
__global__ void __launch_bounds__(256) convert_kernel(
    const float* __restrict__ Wl, const float* __restrict__ x,
    unsigned short* __restrict__ wlb, unsigned short* __restrict__ xb) {
  const long long WL4 = 16777216LL;
  const long long X4  = 524288LL;
  long long i = (long long)blockIdx.x * 256 + threadIdx.x;
  const long long stride = (long long)gridDim.x * 256;
  for (; i < WL4 + X4; i += stride) {
    float4 v;
    if (i < WL4) v = ((const float4*)Wl)[i];
    else         v = ((const float4*)x)[i - WL4];
    ushort4 o;
    o.x = f2bf(v.x); o.y = f2bf(v.y); o.z = f2bf(v.z); o.w = f2bf(v.w);
    if (i < WL4) ((ushort4*)wlb)[i] = o;
    else         ((ushort4*)xb)[i - WL4] = o;
  }
}

// ---------------- kernel 2: routing probabilities (f32 exact) ----------------
__global__ void __launch_bounds__(256) routing_kernel(
    const float* __restrict__ x, const float* __restrict__ Wd,
    const float* __restrict__ bd, float* __restrict__ rt) {
  __shared__ float xs[4][KD];
  __shared__ float sdp[4][64];
  const int tid = threadIdx.x;
  const int b0 = blockIdx.x * 4;
  const float4* xsrc = (const float4*)(x + (size_t)b0 * KD);
  float4* xdst = (float4*)&xs[0][0];
  for (int i = tid; i < KD; i += 256) xdst[i] = xsrc[i];
  __syncthreads();
  const int wv = tid >> 6, ln = tid & 63;
  const int b = b0 + wv;
  if (ln < 63) {
    const float4* wrow = (const float4*)(Wd + (size_t)ln * KD);
    const float4* xr = (const float4*)&xs[wv][0];
    float4 a = {0.f, 0.f, 0.f, 0.f};
    for (int k = 0; k < KD / 4; ++k) {
      float4 w = wrow[k], xv = xr[k];
      a.x += w.x * xv.x; a.y += w.y * xv.y; a.z += w.z * xv.z; a.w += w.w * xv.w;
    }
    float z = a.x + a.y + a.z + a.w + bd[ln];
    sdp[wv][ln] = 1.f / (1.f + __expf(-z));
  }
  __syncthreads();
  float prod = 1.f;
  int node = 0, index = ln;
  for (int d = 0; d < 6; ++d) {
    float pv = sdp[wv][node];
    prod *= (index & 1) ? (1.f - pv) : pv;
    node = node * 2 + 1 + (index & 1);
    index >>= 1;
  }
  rt[(size_t)b * NLEAF + ln] = prod;
}

// ------ kernel 3: 256x256 bf16 GEMM, 4-buffer ring, counted vmcnt(8) ---------
// A = xb [2048][1024], B = wlb base [ntile*256][1024] (N x K), C fp16.
// 8 waves (2M x 4N), per-wave 128x64 output, BK=32, 128 KiB LDS ring of 4.
__global__ void __launch_bounds__(512, 2) gemm_kernel(
    const unsigned short* __restrict__ A, const unsigned short* __restrict__ B,
    _Float16* __restrict__ C, int ntile) {
  extern __shared__ char smem[];   // 4 bufs x 32 KB: {A 16K | B 16K}
  const int tid = threadIdx.x;
  const int w = tid >> 6, ln = tid & 63;
  const int wm = w >> 2, wn = w & 3;
  const int g = ln >> 4, r16 = ln & 15;
  const int bid = blockIdx.x;
  const int j = bid >> 3;                       // XCD-chunked swizzle
  const int bm = (j & 7) * BM;
  const int bn = (((j >> 3) << 3) + (bid & 7)) * BN;
  const long long ldc = (long long)ntile * 256;

  // staging addresses: rows 0..127 (+128 for second issue), chunk-XOR on source
  const int rS = tid >> 2;
  const int cS = tid & 3;
  const int csrc = cS ^ ((rS >> 1) & 3);        // same for rS and rS+128
  const unsigned short* ga0 = A + (size_t)(bm + rS) * KD + csrc * 8;
  const unsigned short* ga1 = ga0 + (size_t)128 * KD;
  const unsigned short* gb0 = B + (size_t)(bn + rS) * KD + csrc * 8;
  const unsigned short* gb1 = gb0 + (size_t)128 * KD;
  const int ldsw = w * 1024;                    // wave-uniform

  auto STAGE = [&](int tile) {
    char* base = smem + (tile & 3) * 32768;
    const size_t ko = (size_t)tile * BKT;
    gload_lds16(ga0 + ko, base + ldsw);
    gload_lds16(ga1 + ko, base + 8192 + ldsw);
    gload_lds16(gb0 + ko, base + 16384 + ldsw);
    gload_lds16(gb1 + ko, base + 24576 + ldsw);
  };

  // per-thread LDS read offsets (swizzle applied on read side too)
  int offA[8], offB[4];
#pragma unroll
  for (int mi = 0; mi < 8; ++mi) {
    const int row = wm * 128 + mi * 16 + r16;
    offA[mi] = row * 64 + (g ^ ((row >> 1) & 3)) * 16;
  }
#pragma unroll
  for (int ni = 0; ni < 4; ++ni) {
    const int row = wn * 64 + ni * 16 + r16;
    offB[ni] = 16384 + row * 64 + (g ^ ((row >> 1) & 3)) * 16;
  }

  f32x4 acc[8][4];
#pragma unroll
  for (int mi = 0; mi < 8; ++mi)
#pragma unroll
    for (int ni = 0; ni < 4; ++ni) acc[mi][ni] = (f32x4){0.f, 0.f, 0.f, 0.f};

  STAGE(0); STAGE(1); STAGE(2);
  asm volatile("s_waitcnt vmcnt(8)" ::: "memory");   // tile 0 landed
  asm volatile("s_barrier" ::: "memory");

  for (int t = 0; t < NKT; ++t) {
    if (t + 3 < NKT) STAGE(t + 3);
    const char* buf = smem + (t & 3) * 32768;
    bf16x8 af[8], bfr[4];
#pragma unroll
    for (int mi = 0; mi < 8; ++mi) af[mi] = *(const bf16x8*)(buf + offA[mi]);
#pragma unroll
    for (int ni = 0; ni < 4; ++ni) bfr[ni] = *(const bf16x8*)(buf + offB[ni]);
    __builtin_amdgcn_s_setprio(1);
#pragma unroll
    for (int mi = 0; mi < 8; ++mi)
#pragma unroll
      for (int ni = 0; ni < 4; ++ni)
        acc[mi][ni] = __builtin_amdgcn_mfma_f32_16x16x32_bf16(
            af[mi], bfr[ni], acc[mi][ni], 0, 0, 0);
    __builtin_amdgcn_s_setprio(0);
    __builtin_amdgcn_sched_barrier(0);   // pin MFMAs (+lgkm waits) before barrier
    if (t + 3 < NKT) {
      asm volatile("s_waitcnt vmcnt(8)" ::: "memory");   // tile t+1 landed
    } else if (t + 2 < NKT) {
      asm volatile("s_waitcnt vmcnt(4)" ::: "memory");
    } else if (t + 1 < NKT) {
      asm volatile("s_waitcnt vmcnt(0)" ::: "memory");
    }
    if (t + 1 < NKT) asm volatile("s_barrier" ::: "memory");
  }

  // epilogue: C/D layout col=r16, row=g*4+q
#pragma unroll
  for (int mi = 0; mi < 8; ++mi)
#pragma unroll
    for (int q = 0; q < 4; ++q) {
      const long long grow = bm + wm * 128 + mi * 16 + g * 4 + q;
#pragma unroll
      for (int ni = 0; ni < 4; ++ni) {
        const int gcol = bn + wn * 64 + ni * 16 + r16;
        C[grow * ldc + gcol] = (_Float16)acc[mi][ni][q];
      }
    }
}

// ------- kernel 4: softmax over each leaf row + routing-weighted reduce -------
__global__ void __launch_bounds__(256) smax_kernel(
    const _Float16* __restrict__ Cg, const float* __restrict__ rt,
    const float* __restrict__ bl, float* __restrict__ out,
    int lpg, int l0, int first) {
  __shared__ float redm[4], reds[4];
  __shared__ float rts[64];
  const int tid = threadIdx.x;
  const int b = blockIdx.x;
  const int w = tid >> 6, ln = tid & 63;
  const int c0 = tid * 4;
  if (tid < lpg) rts[tid] = rt[(size_t)b * NLEAF + l0 + tid];
  __syncthreads();
  float oacc[4] = {0.f, 0.f, 0.f, 0.f};
  const long long ldc = (long long)lpg * ND;

  for (int jj = 0; jj < lpg; ++jj) {
    const int l = l0 + jj;
    const f16x4 h = *(const f16x4*)(Cg + (size_t)b * ldc + jj * ND + c0);
    const float4 blv = *(const float4*)(bl + (size_t)l * ND + c0);
    float v[4];
    v[0] = (float)h[0] + blv.x; v[1] = (float)h[1] + blv.y;
    v[2] = (float)h[2] + blv.z; v[3] = (float)h[3] + blv.w;
    float m = fmaxf(fmaxf(v[0], v[1]), fmaxf(v[2], v[3]));
#pragma unroll
    for (int off = 1; off < 64; off <<= 1) m = fmaxf(m, __shfl_xor(m, off));
    if (ln == 0) redm[w] = m;
    __syncthreads();
    m = fmaxf(fmaxf(redm[0], redm[1]), fmaxf(redm[2], redm[3]));
    float e[4], s = 0.f;
#pragma unroll
    for (int k = 0; k < 4; ++k) { e[k] = __expf(v[k] - m); s += e[k]; }
#pragma unroll
    for (int off = 1; off < 64; off <<= 1) s += __shfl_xor(s, off);
    if (ln == 0) reds[w] = s;
    __syncthreads();
    const float S = reds[0] + reds[1] + reds[2] + reds[3];
    const float coef = rts[jj] / S;
#pragma unroll
    for (int k = 0; k < 4; ++k) oacc[k] += coef * e[k];
  }

  float* orow = out + (size_t)b * ND + c0;
  if (first) {
    *(float4*)orow = (float4){oacc[0], oacc[1], oacc[2], oacc[3]};
  } else {
    float4 p = *(const float4*)orow;
    p.x += oacc[0]; p.y += oacc[1]; p.z += oacc[2]; p.w += oacc[3];
    *(float4*)orow = p;
  }
}

extern "C" void kernel_launch(void* const* d_in, const int* in_sizes, int n_in,
                              void* d_out, int out_size, void* d_ws, size_t ws_size,
                              hipStream_t stream) {
  const float* x  = (const float*)d_in[0];
  const float* Wd = (const float*)d_in[1];
  const float* bd = (const float*)d_in[2];
  const float* Wl = (const float*)d_in[3];
  const float* bl = (const float*)d_in[4];
  float* out = (float*)d_out;
  char* ws = (char*)d_ws;
  unsigned short* wlb = (unsigned short*)(ws + WLB_OFF);
  unsigned short* xb  = (unsigned short*)(ws + XB_OFF);
  float* rt           = (float*)(ws + RT_OFF);
  _Float16* lg        = (_Float16*)(ws + LG_OFF);

  convert_kernel<<<2048, 256, 0, stream>>>(Wl, x, wlb, xb);
  routing_kernel<<<BATCH / 4, 256, 0, stream>>>(x, Wd, bd, rt);
  hipFuncSetAttribute((const void*)gemm_kernel,
                      hipFuncAttributeMaxDynamicSharedMemorySize, 131072);

  const int ngrp = (ws_size >= LG_OFF + (size_t)BATCH * NLEAF * ND * 2) ? 1 : 4;
  const int lpg = NLEAF / ngrp;
  const int ntile = lpg * (ND / BN) * 4 / 4;     // lpg*1024/256
  for (int grp = 0; grp < ngrp; ++grp) {
    gemm_kernel<<<8 * ntile, 512, 131072, stream>>>(
        xb, wlb + (size_t)grp * lpg * ND * KD, lg, ntile);
    smax_kernel<<<BATCH, 256, 0, stream>>>(lg, rt, bl, out,
                                           lpg, grp * lpg, grp == 0);
  }
}

// Round 5
// 507.341 us; speedup vs baseline: 2.0464x; 1.0274x over previous
//
#include <hip/hip_runtime.h>
#include <hip/hip_bf16.h>

#define BATCH 2048
#define KD 1024
#define ND 1024
#define NLEAF 64
#define BM 256
#define BN 256
#define BKT 32              // K elements per pipeline step
#define NKT (KD / BKT)      // 32 steps

typedef __attribute__((ext_vector_type(8))) short bf16x8;
typedef __attribute__((ext_vector_type(4))) float f32x4;
typedef __attribute__((ext_vector_type(4))) _Float16 f16x4;

// workspace layout (bytes)
#define WLB_OFF 0ULL                 // 64M bf16 = 128 MB
#define XB_OFF  134217728ULL         // 2M bf16 = 4 MB
#define RT_OFF  138412032ULL         // 512 KB
#define LG_OFF  138936320ULL         // logits fp16 (268 MB full / 64 MB grouped)

__device__ __forceinline__ unsigned short f2bf(float f) {
  unsigned int u = __float_as_uint(f);
  u += 0x7fffu + ((u >> 16) & 1u);
  return (unsigned short)(u >> 16);
}

__device__ __forceinline__ void gload_lds16(const void* g, void* l) {
  __builtin_amdgcn_global_load_lds(
      (const __attribute__((address_space(1))) unsigned int*)g,
      (__attribute__((address_space(3))) unsigned int*)l, 16, 0, 0);
}

// ---------------- kernel 1: f32 -> bf16 conversion of Wl and x ----------------
__global__ void __launch_bounds__(256) convert_kernel(
    const float* __restrict__ Wl, const float* __restrict__ x,
    unsigned short* __restrict__ wlb, unsigned short* __restrict__ xb) {
  const long long WL4 = 16777216LL;
  const long long X4  = 524288LL;
  long long i = (long long)blockIdx.x * 256 + threadIdx.x;
  const long long stride = (long long)gridDim.x * 256;
  for (; i < WL4 + X4; i += stride) {
    float4 v;
    if (i < WL4) v = ((const float4*)Wl)[i];
    else         v = ((const float4*)x)[i - WL4];
    ushort4 o;
    o.x = f2bf(v.x); o.y = f2bf(v.y); o.z = f2bf(v.z); o.w = f2bf(v.w);
    if (i < WL4) ((ushort4*)wlb)[i] = o;
    else         ((ushort4*)xb)[i - WL4] = o;
  }
}

// ---------------- kernel 2: routing probabilities (f32 exact) ----------------
__global__ void __launch_bounds__(256) routing_kernel(
    const float* __restrict__ x, const float* __restrict__ Wd,
    const float* __restrict__ bd, float* __restrict__ rt) {
  __shared__ float xs[4][KD];
  __shared__ float sdp[4][64];
  const int tid = threadIdx.x;
  const int b0 = blockIdx.x * 4;
  const float4* xsrc = (const float4*)(x + (size_t)b0 * KD);
  float4* xdst = (float4*)&xs[0][0];
  for (int i = tid; i < KD; i += 256) xdst[i] = xsrc[i];
  __syncthreads();
  const int wv = tid >> 6, ln = tid & 63;
  const int b = b0 + wv;
  if (ln < 63) {
    const float4* wrow = (const float4*)(Wd + (size_t)ln * KD);
    const float4* xr = (const float4*)&xs[wv][0];
    float4 a = {0.f, 0.f, 0.f, 0.f};
    for (int k = 0; k < KD / 4; ++k) {
      float4 w = wrow[k], xv = xr[k];
      a.x += w.x * xv.x; a.y += w.y * xv.y; a.z += w.z * xv.z; a.w += w.w * xv.w;
    }
    float z = a.x + a.y + a.z + a.w + bd[ln];
    sdp[wv][ln] = 1.f / (1.f + __expf(-z));
  }
  __syncthreads();
  float prod = 1.f;
  int node = 0, index = ln;
  for (int d = 0; d < 6; ++d) {
    float pv = sdp[wv][node];
    prod *= (index & 1) ? (1.f - pv) : pv;
    node = node * 2 + 1 + (index & 1);
    index >>= 1;
  }
  rt[(size_t)b * NLEAF + ln] = prod;
}

// ------ kernel 3: 256x256 bf16 GEMM, 4-buffer ring, counted vmcnt(8), -------
// ------ 2-phase interleaved K-step (m-half split)                     -------
__global__ void __launch_bounds__(512, 2) gemm_kernel(
    const unsigned short* __restrict__ A, const unsigned short* __restrict__ B,
    _Float16* __restrict__ C, int ntile) {
  extern __shared__ char smem[];   // 4 bufs x 32 KB: {A 16K | B 16K}
  const int tid = threadIdx.x;
  const int w = tid >> 6, ln = tid & 63;
  const int wm = w >> 2, wn = w & 3;
  const int g = ln >> 4, r16 = ln & 15;
  const int bid = blockIdx.x;
  const int j = bid >> 3;                       // XCD-chunked swizzle
  const int bm = (j & 7) * BM;
  const int bn = (((j >> 3) << 3) + (bid & 7)) * BN;
  const long long ldc = (long long)ntile * 256;

  // staging addresses: rows 0..127 (+128 second pass), chunk-XOR on source
  const int rS = tid >> 2;
  const int cS = tid & 3;
  const int csrc = cS ^ ((rS >> 1) & 3);
  const unsigned short* ga0 = A + (size_t)(bm + rS) * KD + csrc * 8;
  const unsigned short* ga1 = ga0 + (size_t)128 * KD;
  const unsigned short* gb0 = B + (size_t)(bn + rS) * KD + csrc * 8;
  const unsigned short* gb1 = gb0 + (size_t)128 * KD;
  const int ldsw = w * 1024;                    // wave-uniform

  auto STAGE_A = [&](int tile) {
    char* base = smem + (tile & 3) * 32768;
    const size_t ko = (size_t)tile * BKT;
    gload_lds16(ga0 + ko, base + ldsw);
    gload_lds16(ga1 + ko, base + 8192 + ldsw);
  };
  auto STAGE_B = [&](int tile) {
    char* base = smem + (tile & 3) * 32768;
    const size_t ko = (size_t)tile * BKT;
    gload_lds16(gb0 + ko, base + 16384 + ldsw);
    gload_lds16(gb1 + ko, base + 24576 + ldsw);
  };

  // per-thread LDS read offsets (swizzle on read side too)
  int offA[8], offB[4];
#pragma unroll
  for (int mi = 0; mi < 8; ++mi) {
    const int row = wm * 128 + mi * 16 + r16;
    offA[mi] = row * 64 + (g ^ ((row >> 1) & 3)) * 16;
  }
#pragma unroll
  for (int ni = 0; ni < 4; ++ni) {
    const int row = wn * 64 + ni * 16 + r16;
    offB[ni] = 16384 + row * 64 + (g ^ ((row >> 1) & 3)) * 16;
  }

  f32x4 acc[8][4];
#pragma unroll
  for (int mi = 0; mi < 8; ++mi)
#pragma unroll
    for (int ni = 0; ni < 4; ++ni) acc[mi][ni] = (f32x4){0.f, 0.f, 0.f, 0.f};

  STAGE_A(0); STAGE_B(0);
  STAGE_A(1); STAGE_B(1);
  STAGE_A(2); STAGE_B(2);
  asm volatile("s_waitcnt vmcnt(8)" ::: "memory");   // tile 0 landed
  asm volatile("s_barrier" ::: "memory");

  for (int t = 0; t < NKT; ++t) {
    const char* buf = smem + (t & 3) * 32768;
    bf16x8 af[4], bfr[4];
    // ---- phase 0: B all + A m0-3; stage A-half; MFMA lower m-half ----
#pragma unroll
    for (int ni = 0; ni < 4; ++ni) bfr[ni] = *(const bf16x8*)(buf + offB[ni]);
#pragma unroll
    for (int mi = 0; mi < 4; ++mi) af[mi] = *(const bf16x8*)(buf + offA[mi]);
    if (t + 3 < NKT) STAGE_A(t + 3);
    asm volatile("s_barrier" ::: "memory");
    asm volatile("s_waitcnt lgkmcnt(0)" ::: "memory");
    __builtin_amdgcn_sched_barrier(0);
    __builtin_amdgcn_s_setprio(1);
#pragma unroll
    for (int mi = 0; mi < 4; ++mi)
#pragma unroll
      for (int ni = 0; ni < 4; ++ni)
        acc[mi][ni] = __builtin_amdgcn_mfma_f32_16x16x32_bf16(
            af[mi], bfr[ni], acc[mi][ni], 0, 0, 0);
    __builtin_amdgcn_s_setprio(0);
    __builtin_amdgcn_sched_barrier(0);
    // ---- phase 1: A m4-7; stage B-half; MFMA upper m-half ----
#pragma unroll
    for (int mi = 0; mi < 4; ++mi) af[mi] = *(const bf16x8*)(buf + offA[mi + 4]);
    if (t + 3 < NKT) STAGE_B(t + 3);
    asm volatile("s_barrier" ::: "memory");
    asm volatile("s_waitcnt lgkmcnt(0)" ::: "memory");
    __builtin_amdgcn_sched_barrier(0);
    __builtin_amdgcn_s_setprio(1);
#pragma unroll
    for (int mi = 0; mi < 4; ++mi)
#pragma unroll
      for (int ni = 0; ni < 4; ++ni)
        acc[mi + 4][ni] = __builtin_amdgcn_mfma_f32_16x16x32_bf16(
            af[mi], bfr[ni], acc[mi + 4][ni], 0, 0, 0);
    __builtin_amdgcn_s_setprio(0);
    __builtin_amdgcn_sched_barrier(0);
    if (t + 3 < NKT) {
      asm volatile("s_waitcnt vmcnt(8)" ::: "memory");   // tile t+1 landed
    } else if (t + 2 < NKT) {
      asm volatile("s_waitcnt vmcnt(4)" ::: "memory");
    } else if (t + 1 < NKT) {
      asm volatile("s_waitcnt vmcnt(0)" ::: "memory");
    }
    if (t + 1 < NKT) asm volatile("s_barrier" ::: "memory");
  }

  // epilogue: C/D layout col=r16, row=g*4+q
#pragma unroll
  for (int mi = 0; mi < 8; ++mi)
#pragma unroll
    for (int q = 0; q < 4; ++q) {
      const long long grow = bm + wm * 128 + mi * 16 + g * 4 + q;
#pragma unroll
      for (int ni = 0; ni < 4; ++ni) {
        const int gcol = bn + wn * 64 + ni * 16 + r16;
        C[grow * ldc + gcol] = (_Float16)acc[mi][ni][q];
      }
    }
}

// ------- kernel 4: softmax (no-max-sub, |logit|<~5) + weighted reduce -------
__global__ void __launch_bounds__(256) smax_kernel(
    const _Float16* __restrict__ Cg, const float* __restrict__ rt,
    const float* __restrict__ bl, float* __restrict__ out,
    int lpg, int l0, int first) {
  __shared__ float reds[2][2][4];   // [parity][leaf-in-pair][wave]
  __shared__ float rts[64];
  const int tid = threadIdx.x;
  const int b = blockIdx.x;
  const int w = tid >> 6, ln = tid & 63;
  const int c0 = tid * 4;
  if (tid < lpg) rts[tid] = rt[(size_t)b * NLEAF + l0 + tid];
  __syncthreads();
  float oacc[4] = {0.f, 0.f, 0.f, 0.f};
  const long long ldc = (long long)lpg * ND;

  for (int jj = 0; jj < lpg; jj += 2) {
    const int par = (jj >> 1) & 1;
    const f16x4 h0 = *(const f16x4*)(Cg + (size_t)b * ldc + jj * ND + c0);
    const f16x4 h1 = *(const f16x4*)(Cg + (size_t)b * ldc + (jj + 1) * ND + c0);
    const float4 bv0 = *(const float4*)(bl + (size_t)(l0 + jj) * ND + c0);
    const float4 bv1 = *(const float4*)(bl + (size_t)(l0 + jj + 1) * ND + c0);
    float e0[4], e1[4], s0 = 0.f, s1 = 0.f;
    e0[0] = __expf((float)h0[0] + bv0.x); e0[1] = __expf((float)h0[1] + bv0.y);
    e0[2] = __expf((float)h0[2] + bv0.z); e0[3] = __expf((float)h0[3] + bv0.w);
    e1[0] = __expf((float)h1[0] + bv1.x); e1[1] = __expf((float)h1[1] + bv1.y);
    e1[2] = __expf((float)h1[2] + bv1.z); e1[3] = __expf((float)h1[3] + bv1.w);
#pragma unroll
    for (int k = 0; k < 4; ++k) { s0 += e0[k]; s1 += e1[k]; }
#pragma unroll
    for (int off = 1; off < 64; off <<= 1) {
      s0 += __shfl_xor(s0, off);
      s1 += __shfl_xor(s1, off);
    }
    if (ln == 0) { reds[par][0][w] = s0; reds[par][1][w] = s1; }
    __syncthreads();
    const float S0 = reds[par][0][0] + reds[par][0][1] + reds[par][0][2] + reds[par][0][3];
    const float S1 = reds[par][1][0] + reds[par][1][1] + reds[par][1][2] + reds[par][1][3];
    const float c0f = rts[jj] / S0;
    const float c1f = rts[jj + 1] / S1;
#pragma unroll
    for (int k = 0; k < 4; ++k) oacc[k] += c0f * e0[k] + c1f * e1[k];
  }

  float* orow = out + (size_t)b * ND + c0;
  if (first) {
    *(float4*)orow = (float4){oacc[0], oacc[1], oacc[2], oacc[3]};
  } else {
    float4 p = *(const float4*)orow;
    p.x += oacc[0]; p.y += oacc[1]; p.z += oacc[2]; p.w += oacc[3];
    *(float4*)orow = p;
  }
}

extern "C" void kernel_launch(void* const* d_in, const int* in_sizes, int n_in,
                              void* d_out, int out_size, void* d_ws, size_t ws_size,
                              hipStream_t stream) {
  const float* x  = (const float*)d_in[0];
  const float* Wd = (const float*)d_in[1];
  const float* bd = (const float*)d_in[2];
  const float* Wl = (const float*)d_in[3];
  const float* bl = (const float*)d_in[4];
  float* out = (float*)d_out;
  char* ws = (char*)d_ws;
  unsigned short* wlb = (unsigned short*)(ws + WLB_OFF);
  unsigned short* xb  = (unsigned short*)(ws + XB_OFF);
  float* rt           = (float*)(ws + RT_OFF);
  _Float16* lg        = (_Float16*)(ws + LG_OFF);

  convert_kernel<<<2048, 256, 0, stream>>>(Wl, x, wlb, xb);
  routing_kernel<<<BATCH / 4, 256, 0, stream>>>(x, Wd, bd, rt);
  hipFuncSetAttribute((const void*)gemm_kernel,
                      hipFuncAttributeMaxDynamicSharedMemorySize, 131072);

  const int ngrp = (ws_size >= LG_OFF + (size_t)BATCH * NLEAF * ND * 2) ? 1 : 4;
  const int lpg = NLEAF / ngrp;
  const int ntile = lpg * (ND / BN);
  for (int grp = 0; grp < ngrp; ++grp) {
    gemm_kernel<<<8 * ntile, 512, 131072, stream>>>(
        xb, wlb + (size_t)grp * lpg * ND * KD, lg, ntile);
    smax_kernel<<<BATCH, 256, 0, stream>>>(lg, rt, bl, out,
                                           lpg, grp * lpg, grp == 0);
  }
}

// Round 6
// 499.834 us; speedup vs baseline: 2.0771x; 1.0150x over previous
//
#include <hip/hip_runtime.h>
#include <hip/hip_bf16.h>

#define BATCH 2048
#define KD 1024
#define ND 1024
#define NLEAF 64
#define BM 256
#define BN 256
#define BKT 64              // K elements per tile
#define NT (KD / BKT)       // 16 tiles

typedef __attribute__((ext_vector_type(8))) short bf16x8;
typedef __attribute__((ext_vector_type(4))) float f32x4;
typedef __attribute__((ext_vector_type(4))) _Float16 f16x4;

// workspace layout (bytes)
#define WLB_OFF 0ULL                 // 64M bf16 = 128 MB
#define XB_OFF  134217728ULL         // 2M bf16 = 4 MB
#define RT_OFF  138412032ULL         // 512 KB
#define LG_OFF  138936320ULL         // logits fp16 (268 MB full / 64 MB grouped)

__device__ __forceinline__ unsigned short f2bf(float f) {
  unsigned int u = __float_as_uint(f);
  u += 0x7fffu + ((u >> 16) & 1u);
  return (unsigned short)(u >> 16);
}

__device__ __forceinline__ void gload_lds16(const void* g, void* l) {
  __builtin_amdgcn_global_load_lds(
      (const __attribute__((address_space(1))) unsigned int*)g,
      (__attribute__((address_space(3))) unsigned int*)l, 16, 0, 0);
}

// ---------------- kernel 1: f32 -> bf16 conversion of Wl and x ----------------
__global__ void __launch_bounds__(256) convert_kernel(
    const float* __restrict__ Wl, const float* __restrict__ x,
    unsigned short* __restrict__ wlb, unsigned short* __restrict__ xb) {
  const long long WL4 = 16777216LL;
  const long long X4  = 524288LL;
  long long i = (long long)blockIdx.x * 256 + threadIdx.x;
  const long long stride = (long long)gridDim.x * 256;
  for (; i < WL4 + X4; i += stride) {
    float4 v;
    if (i < WL4) v = ((const float4*)Wl)[i];
    else         v = ((const float4*)x)[i - WL4];
    ushort4 o;
    o.x = f2bf(v.x); o.y = f2bf(v.y); o.z = f2bf(v.z); o.w = f2bf(v.w);
    if (i < WL4) ((ushort4*)wlb)[i] = o;
    else         ((ushort4*)xb)[i - WL4] = o;
  }
}

// ---------------- kernel 2: routing probabilities (f32 exact) ----------------
__global__ void __launch_bounds__(256) routing_kernel(
    const float* __restrict__ x, const float* __restrict__ Wd,
    const float* __restrict__ bd, float* __restrict__ rt) {
  __shared__ float xs[4][KD];
  __shared__ float sdp[4][64];
  const int tid = threadIdx.x;
  const int b0 = blockIdx.x * 4;
  const float4* xsrc = (const float4*)(x + (size_t)b0 * KD);
  float4* xdst = (float4*)&xs[0][0];
  for (int i = tid; i < KD; i += 256) xdst[i] = xsrc[i];
  __syncthreads();
  const int wv = tid >> 6, ln = tid & 63;
  const int b = b0 + wv;
  if (ln < 63) {
    const float4* wrow = (const float4*)(Wd + (size_t)ln * KD);
    const float4* xr = (const float4*)&xs[wv][0];
    float4 a = {0.f, 0.f, 0.f, 0.f};
    for (int k = 0; k < KD / 4; ++k) {
      float4 w = wrow[k], xv = xr[k];
      a.x += w.x * xv.x; a.y += w.y * xv.y; a.z += w.z * xv.z; a.w += w.w * xv.w;
    }
    float z = a.x + a.y + a.z + a.w + bd[ln];
    sdp[wv][ln] = 1.f / (1.f + __expf(-z));
  }
  __syncthreads();
  float prod = 1.f;
  int node = 0, index = ln;
  for (int d = 0; d < 6; ++d) {
    float pv = sdp[wv][node];
    prod *= (index & 1) ? (1.f - pv) : pv;
    node = node * 2 + 1 + (index & 1);
    index >>= 1;
  }
  rt[(size_t)b * NLEAF + ln] = prod;
}

// ------ kernel 3: 256x256 bf16 GEMM, 8-phase schedule (m201 template) --------
// BK=64 tiles; 2 x 64KB LDS buffers, each = {A-k0, A-k1, B-k0, B-k1} 16KB
// regions (64B rows, chunk-XOR swizzled). 4 phases per tile:
//   P1 {readB0+A0lo, stage Ak0(t+1)}  P2 {readA0hi, stage Bk0(t+1), vmcnt4}
//   P3 {readB1+A1lo, stage Ak1(t+1)}  P4 {readA1hi, stage Bk1(t+1), vmcnt4}
// counted vmcnt before the phase-end barrier; never drain-0 mid-loop.
__global__ void __launch_bounds__(512, 2) gemm_kernel(
    const unsigned short* __restrict__ A, const unsigned short* __restrict__ B,
    _Float16* __restrict__ C, int ntile) {
  extern __shared__ char smem[];
  const int tid = threadIdx.x;
  const int w = tid >> 6, ln = tid & 63;
  const int wm = w >> 2, wn = w & 3;
  const int g = ln >> 4, r16 = ln & 15;
  const int bid = blockIdx.x;
  const int j = bid >> 3;                       // XCD-chunked swizzle
  const int bm = (j & 7) * BM;
  const int bn = (((j >> 3) << 3) + (bid & 7)) * BN;
  const long long ldc = (long long)ntile * 256;

  // staging: thread -> (row rS in 0..127 [+128 on 2nd load], 16B chunk cS)
  const int rS = tid >> 2;
  const int cS = tid & 3;
  const int csrc = cS ^ ((rS >> 1) & 3);        // both-sides swizzle, source
  const unsigned short* ga0 = A + (size_t)(bm + rS) * KD + csrc * 8;
  const unsigned short* ga1 = ga0 + (size_t)128 * KD;
  const unsigned short* gb0 = B + (size_t)(bn + rS) * KD + csrc * 8;
  const unsigned short* gb1 = gb0 + (size_t)128 * KD;
  const int ldsw = w * 1024;                    // wave-uniform dest offset

  // region: 0=A-k0, 1=A-k1, 2=B-k0, 3=B-k1 (16 KB each within 64KB buffer)
  auto STAGE_H = [&](int tile, int region) {
    char* base = smem + (tile & 1) * 65536 + region * 16384;
    const unsigned short* g0 = (region >= 2) ? gb0 : ga0;
    const unsigned short* g1 = (region >= 2) ? gb1 : ga1;
    const size_t ko = (size_t)tile * BKT + (region & 1) * 32;
    gload_lds16(g0 + ko, base + ldsw);           // rows 0..127
    gload_lds16(g1 + ko, base + 8192 + ldsw);    // rows 128..255
  };

  // per-thread LDS read offsets within a 16KB half (64B rows, read-side swz)
  int offA[8], offB[4];
#pragma unroll
  for (int mi = 0; mi < 8; ++mi) {
    const int row = wm * 128 + mi * 16 + r16;
    offA[mi] = row * 64 + ((g ^ ((row >> 1) & 3)) * 16);
  }
#pragma unroll
  for (int ni = 0; ni < 4; ++ni) {
    const int row = wn * 64 + ni * 16 + r16;
    offB[ni] = row * 64 + ((g ^ ((row >> 1) & 3)) * 16);
  }

  f32x4 acc[8][4];
#pragma unroll
  for (int mi = 0; mi < 8; ++mi)
#pragma unroll
    for (int ni = 0; ni < 4; ++ni) acc[mi][ni] = (f32x4){0.f, 0.f, 0.f, 0.f};

  // prologue: stage tile0 fully (order a0,b0,a1,b1); wait first two halves
  STAGE_H(0, 0); STAGE_H(0, 2); STAGE_H(0, 1); STAGE_H(0, 3);
  asm volatile("s_waitcnt vmcnt(4)" ::: "memory");
  asm volatile("s_barrier" ::: "memory");

  for (int t = 0; t < NT; ++t) {
    const bool pf = (t + 1 < NT);
    const char* bufp = smem + (t & 1) * 65536;
    bf16x8 af[4], bfr[4];

    // ---------------- P1: kk0, mi 0-3 ----------------
#pragma unroll
    for (int ni = 0; ni < 4; ++ni)
      bfr[ni] = *(const bf16x8*)(bufp + 32768 + offB[ni]);
#pragma unroll
    for (int mi = 0; mi < 4; ++mi)
      af[mi] = *(const bf16x8*)(bufp + offA[mi]);
    if (pf) STAGE_H(t + 1, 0);
    asm volatile("s_barrier" ::: "memory");
    asm volatile("s_waitcnt lgkmcnt(0)" ::: "memory");
    __builtin_amdgcn_sched_barrier(0);
    __builtin_amdgcn_s_setprio(1);
#pragma unroll
    for (int mi = 0; mi < 4; ++mi)
#pragma unroll
      for (int ni = 0; ni < 4; ++ni)
        acc[mi][ni] = __builtin_amdgcn_mfma_f32_16x16x32_bf16(
            af[mi], bfr[ni], acc[mi][ni], 0, 0, 0);
    __builtin_amdgcn_s_setprio(0);
    __builtin_amdgcn_sched_barrier(0);
    asm volatile("s_barrier" ::: "memory");

    // ---------------- P2: kk0, mi 4-7 ----------------
#pragma unroll
    for (int mi = 0; mi < 4; ++mi)
      af[mi] = *(const bf16x8*)(bufp + offA[mi + 4]);
    if (pf) STAGE_H(t + 1, 2);
    asm volatile("s_barrier" ::: "memory");
    asm volatile("s_waitcnt lgkmcnt(0)" ::: "memory");
    __builtin_amdgcn_sched_barrier(0);
    __builtin_amdgcn_s_setprio(1);
#pragma unroll
    for (int mi = 0; mi < 4; ++mi)
#pragma unroll
      for (int ni = 0; ni < 4; ++ni)
        acc[mi + 4][ni] = __builtin_amdgcn_mfma_f32_16x16x32_bf16(
            af[mi], bfr[ni], acc[mi + 4][ni], 0, 0, 0);
    __builtin_amdgcn_s_setprio(0);
    __builtin_amdgcn_sched_barrier(0);
    if (pf) asm volatile("s_waitcnt vmcnt(4)" ::: "memory");  // a1,b1(t) landed
    else    asm volatile("s_waitcnt vmcnt(0)" ::: "memory");
    asm volatile("s_barrier" ::: "memory");

    // ---------------- P3: kk1, mi 0-3 ----------------
#pragma unroll
    for (int ni = 0; ni < 4; ++ni)
      bfr[ni] = *(const bf16x8*)(bufp + 49152 + offB[ni]);
#pragma unroll
    for (int mi = 0; mi < 4; ++mi)
      af[mi] = *(const bf16x8*)(bufp + 16384 + offA[mi]);
    if (pf) STAGE_H(t + 1, 1);
    asm volatile("s_barrier" ::: "memory");
    asm volatile("s_waitcnt lgkmcnt(0)" ::: "memory");
    __builtin_amdgcn_sched_barrier(0);
    __builtin_amdgcn_s_setprio(1);
#pragma unroll
    for (int mi = 0; mi < 4; ++mi)
#pragma unroll
      for (int ni = 0; ni < 4; ++ni)
        acc[mi][ni] = __builtin_amdgcn_mfma_f32_16x16x32_bf16(
            af[mi], bfr[ni], acc[mi][ni], 0, 0, 0);
    __builtin_amdgcn_s_setprio(0);
    __builtin_amdgcn_sched_barrier(0);
    asm volatile("s_barrier" ::: "memory");

    // ---------------- P4: kk1, mi 4-7 ----------------
#pragma unroll
    for (int mi = 0; mi < 4; ++mi)
      af[mi] = *(const bf16x8*)(bufp + 16384 + offA[mi + 4]);
    if (pf) STAGE_H(t + 1, 3);
    asm volatile("s_barrier" ::: "memory");
    asm volatile("s_waitcnt lgkmcnt(0)" ::: "memory");
    __builtin_amdgcn_sched_barrier(0);
    __builtin_amdgcn_s_setprio(1);
#pragma unroll
    for (int mi = 0; mi < 4; ++mi)
#pragma unroll
      for (int ni = 0; ni < 4; ++ni)
        acc[mi + 4][ni] = __builtin_amdgcn_mfma_f32_16x16x32_bf16(
            af[mi], bfr[ni], acc[mi + 4][ni], 0, 0, 0);
    __builtin_amdgcn_s_setprio(0);
    __builtin_amdgcn_sched_barrier(0);
    if (pf) {
      asm volatile("s_waitcnt vmcnt(4)" ::: "memory");  // a0,b0(t+1) landed
      asm volatile("s_barrier" ::: "memory");
    }
  }

  // epilogue: C/D layout col=r16, row=g*4+q (byte-identical to round 4/5)
#pragma unroll
  for (int mi = 0; mi < 8; ++mi)
#pragma unroll
    for (int q = 0; q < 4; ++q) {
      const long long grow = bm + wm * 128 + mi * 16 + g * 4 + q;
#pragma unroll
      for (int ni = 0; ni < 4; ++ni) {
        const int gcol = bn + wn * 64 + ni * 16 + r16;
        C[grow * ldc + gcol] = (_Float16)acc[mi][ni][q];
      }
    }
}

// ------- kernel 4: softmax (no-max-sub, |logit|<~5) + weighted reduce -------
__global__ void __launch_bounds__(256) smax_kernel(
    const _Float16* __restrict__ Cg, const float* __restrict__ rt,
    const float* __restrict__ bl, float* __restrict__ out,
    int lpg, int l0, int first) {
  __shared__ float reds[2][2][4];   // [parity][leaf-in-pair][wave]
  __shared__ float rts[64];
  const int tid = threadIdx.x;
  const int b = blockIdx.x;
  const int w = tid >> 6, ln = tid & 63;
  const int c0 = tid * 4;
  if (tid < lpg) rts[tid] = rt[(size_t)b * NLEAF + l0 + tid];
  __syncthreads();
  float oacc[4] = {0.f, 0.f, 0.f, 0.f};
  const long long ldc = (long long)lpg * ND;

  for (int jj = 0; jj < lpg; jj += 2) {
    const int par = (jj >> 1) & 1;
    const f16x4 h0 = *(const f16x4*)(Cg + (size_t)b * ldc + jj * ND + c0);
    const f16x4 h1 = *(const f16x4*)(Cg + (size_t)b * ldc + (jj + 1) * ND + c0);
    const float4 bv0 = *(const float4*)(bl + (size_t)(l0 + jj) * ND + c0);
    const float4 bv1 = *(const float4*)(bl + (size_t)(l0 + jj + 1) * ND + c0);
    float e0[4], e1[4], s0 = 0.f, s1 = 0.f;
    e0[0] = __expf((float)h0[0] + bv0.x); e0[1] = __expf((float)h0[1] + bv0.y);
    e0[2] = __expf((float)h0[2] + bv0.z); e0[3] = __expf((float)h0[3] + bv0.w);
    e1[0] = __expf((float)h1[0] + bv1.x); e1[1] = __expf((float)h1[1] + bv1.y);
    e1[2] = __expf((float)h1[2] + bv1.z); e1[3] = __expf((float)h1[3] + bv1.w);
#pragma unroll
    for (int k = 0; k < 4; ++k) { s0 += e0[k]; s1 += e1[k]; }
#pragma unroll
    for (int off = 1; off < 64; off <<= 1) {
      s0 += __shfl_xor(s0, off);
      s1 += __shfl_xor(s1, off);
    }
    if (ln == 0) { reds[par][0][w] = s0; reds[par][1][w] = s1; }
    __syncthreads();
    const float S0 = reds[par][0][0] + reds[par][0][1] + reds[par][0][2] + reds[par][0][3];
    const float S1 = reds[par][1][0] + reds[par][1][1] + reds[par][1][2] + reds[par][1][3];
    const float c0f = rts[jj] / S0;
    const float c1f = rts[jj + 1] / S1;
#pragma unroll
    for (int k = 0; k < 4; ++k) oacc[k] += c0f * e0[k] + c1f * e1[k];
  }

  float* orow = out + (size_t)b * ND + c0;
  if (first) {
    *(float4*)orow = (float4){oacc[0], oacc[1], oacc[2], oacc[3]};
  } else {
    float4 p = *(const float4*)orow;
    p.x += oacc[0]; p.y += oacc[1]; p.z += oacc[2]; p.w += oacc[3];
    *(float4*)orow = p;
  }
}

extern "C" void kernel_launch(void* const* d_in, const int* in_sizes, int n_in,
                              void* d_out, int out_size, void* d_ws, size_t ws_size,
                              hipStream_t stream) {
  const float* x  = (const float*)d_in[0];
  const float* Wd = (const float*)d_in[1];
  const float* bd = (const float*)d_in[2];
  const float* Wl = (const float*)d_in[3];
  const float* bl = (const float*)d_in[4];
  float* out = (float*)d_out;
  char* ws = (char*)d_ws;
  unsigned short* wlb = (unsigned short*)(ws + WLB_OFF);
  unsigned short* xb  = (unsigned short*)(ws + XB_OFF);
  float* rt           = (float*)(ws + RT_OFF);
  _Float16* lg        = (_Float16*)(ws + LG_OFF);

  convert_kernel<<<2048, 256, 0, stream>>>(Wl, x, wlb, xb);
  routing_kernel<<<BATCH / 4, 256, 0, stream>>>(x, Wd, bd, rt);
  hipFuncSetAttribute((const void*)gemm_kernel,
                      hipFuncAttributeMaxDynamicSharedMemorySize, 131072);

  const int ngrp = (ws_size >= LG_OFF + (size_t)BATCH * NLEAF * ND * 2) ? 1 : 4;
  const int lpg = NLEAF / ngrp;
  const int ntile = lpg * (ND / BN);
  for (int grp = 0; grp < ngrp; ++grp) {
    gemm_kernel<<<8 * ntile, 512, 131072, stream>>>(
        xb, wlb + (size_t)grp * lpg * ND * KD, lg, ntile);
    smax_kernel<<<BATCH, 256, 0, stream>>>(lg, rt, bl, out,
                                           lpg, grp * lpg, grp == 0);
  }
}